// Round 2
// baseline (1992.383 us; speedup 1.0000x reference)
//
#include <hip/hip_runtime.h>

// EMA recurrence y_t = b*x_t + (1-b)*y_{t-1}, y_{-1}=0, (B,T,U)=(32,4096,512).
//
// Single-pass chained scan (decoupled lookback), exploiting time-constant
// decay a = 1-b so a chunk of length L composes with a^L:
//   - grid = B*C blocks, chunk L = T/C timesteps.
//   - block = 256 threads = 128 float4 channel-groups x 2 time-halves;
//     each thread holds its 16 timesteps of x in REGISTERS (single HBM read).
//   - publish chunk partial S (flag=1), lookback with weights a^(L*j) until an
//     inclusive record (flag=2), publish inclusive, replay scan from registers
//     seeded with the carry-in, stream y out.
//   - atomic ticket => chunk order follows scheduling order => deadlock-free;
//     every block publishes flag=1 after bounded work (no waits before it),
//     so lookback terminates even in the worst schedule.
// Fallbacks (smaller ws): 3-pass chunked scan, then fully-sequential.

namespace {

constexpr int kB  = 32;
constexpr int kT  = 4096;
constexpr int kU  = 512;
constexpr int kU4 = kU / 4;      // 128 float4 channel groups

// ---- single-pass params ----
constexpr int kC1 = 128;         // chunks along T
constexpr int kL1 = kT / kC1;    // 32 timesteps per chunk
constexpr int kH1 = kL1 / 2;     // 16 timesteps per thread (per half)

// ws layout (single-pass)
constexpr size_t kFlagsOff   = 256;                          // ticket in [0,4)
constexpr size_t kFlagsBytes = (size_t)kB * kC1 * 4;         // 16 KiB
constexpr size_t kSpartOff   = kFlagsOff + kFlagsBytes;      // 16640 (256-mult)
constexpr size_t kVecBytes   = (size_t)kB * kC1 * kU * 4;    // 8 MiB
constexpr size_t kEinclOff   = kSpartOff + kVecBytes;
constexpr size_t kOnePassNeed = kEinclOff + kVecBytes;       // ~16.02 MiB

// ---- 3-pass fallback params ----
constexpr int kC3 = 64;
constexpr int kL3 = kT / kC3;    // 64

__device__ __forceinline__ float4 f4_fma(float4 a, float4 b, float4 c) {
  return make_float4(fmaf(a.x, b.x, c.x), fmaf(a.y, b.y, c.y),
                     fmaf(a.z, b.z, c.z), fmaf(a.w, b.w, c.w));
}
__device__ __forceinline__ float4 f4_mul(float4 a, float4 b) {
  return make_float4(a.x * b.x, a.y * b.y, a.z * b.z, a.w * b.w);
}

__device__ __forceinline__ void f4_store_agent(float4* p, float4 v) {
  union { float2 f; unsigned long long u; } c0, c1;
  c0.f = make_float2(v.x, v.y);
  c1.f = make_float2(v.z, v.w);
  unsigned long long* q = reinterpret_cast<unsigned long long*>(p);
  __hip_atomic_store(q + 0, c0.u, __ATOMIC_RELAXED, __HIP_MEMORY_SCOPE_AGENT);
  __hip_atomic_store(q + 1, c1.u, __ATOMIC_RELAXED, __HIP_MEMORY_SCOPE_AGENT);
}
__device__ __forceinline__ float4 f4_load_agent(const float4* p) {
  const unsigned long long* q = reinterpret_cast<const unsigned long long*>(p);
  union { float2 f; unsigned long long u; } c0, c1;
  c0.u = __hip_atomic_load(q + 0, __ATOMIC_RELAXED, __HIP_MEMORY_SCOPE_AGENT);
  c1.u = __hip_atomic_load(q + 1, __ATOMIC_RELAXED, __HIP_MEMORY_SCOPE_AGENT);
  return make_float4(c0.f.x, c0.f.y, c1.f.x, c1.f.y);
}

__global__ __launch_bounds__(256) void ema_zero_ws(unsigned* w, int n) {
  int i = blockIdx.x * 256 + threadIdx.x;
  if (i < n) w[i] = 0u;
}

__global__ __launch_bounds__(256, 3) void ema_onepass(
    const float* __restrict__ x, const float* __restrict__ bc,
    float* __restrict__ out, unsigned* ticket, unsigned* flags,
    float4* Spart, float4* Eincl) {
  __shared__ float4 lds_s0[kU4];
  __shared__ float4 lds_e[kU4];
  __shared__ unsigned lds_ticket;

  const int tid = threadIdx.x;
  if (tid == 0) lds_ticket = atomicAdd(ticket, 1u);
  __syncthreads();
  const unsigned t = lds_ticket;
  const int b    = (int)(t & 31u);   // kB = 32
  const int k    = (int)(t >> 5);    // [0, kC1)
  const int u4   = tid & (kU4 - 1);
  const int half = tid >> 7;         // 0: steps [0,16), 1: steps [16,32)

  const float4 bb = reinterpret_cast<const float4*>(bc)[u4];
  const float4 a4 = make_float4(1.f - bb.x, 1.f - bb.y, 1.f - bb.z, 1.f - bb.w);
  float4 a16 = a4;
  #pragma unroll
  for (int j = 0; j < 4; ++j) a16 = f4_mul(a16, a16);      // a^16
  const float4 a32 = f4_mul(a16, a16);                      // a^L

  const size_t rowoff =
      ((size_t)b * kT + (size_t)k * kL1 + (size_t)half * kH1) * kU4 + u4;
  const float4* xp = reinterpret_cast<const float4*>(x) + rowoff;

  // ---- sweep 1: load sub-chunk into registers, local zero-init scan final
  float4 xv[kH1];
  #pragma unroll
  for (int i = 0; i < kH1; ++i) xv[i] = xp[(size_t)i * kU4];
  float4 s = make_float4(0.f, 0.f, 0.f, 0.f);
  #pragma unroll
  for (int i = 0; i < kH1; ++i) s = f4_fma(a4, s, f4_mul(bb, xv[i]));

  if (half == 0) lds_s0[u4] = s;
  __syncthreads();

  const int cidx = b * kC1 + k;
  float4 S = make_float4(0.f, 0.f, 0.f, 0.f);  // chunk partial (half1 only)
  if (half == 1) {
    const float4 s0 = lds_s0[u4];
    S = f4_fma(a16, s0, s);
    f4_store_agent(&Spart[(size_t)cidx * kU4 + u4], S);
  }
  __threadfence();
  __syncthreads();
  if (tid == 0)
    __hip_atomic_store(&flags[cidx], 1u, __ATOMIC_RELEASE,
                       __HIP_MEMORY_SCOPE_AGENT);

  // ---- lookback: compute carry-in E (state after step k*L-1), half1 only
  float4 Ein = make_float4(0.f, 0.f, 0.f, 0.f);
  if (half == 1 && k > 0) {
    float4 w = make_float4(1.f, 1.f, 1.f, 1.f);
    int j = k - 1;
    for (;;) {
      const unsigned* fp = &flags[b * kC1 + j];
      unsigned f = __hip_atomic_load(fp, __ATOMIC_ACQUIRE,
                                     __HIP_MEMORY_SCOPE_AGENT);
      while (f == 0u) {
        __builtin_amdgcn_s_sleep(1);
        f = __hip_atomic_load(fp, __ATOMIC_ACQUIRE, __HIP_MEMORY_SCOPE_AGENT);
      }
      const float4* src = (f >= 2u ? Eincl : Spart);
      const float4 v = f4_load_agent(&src[((size_t)b * kC1 + j) * kU4 + u4]);
      Ein = f4_fma(w, v, Ein);
      if (f >= 2u || j == 0) break;
      w = f4_mul(w, a32);
      --j;
    }
  }

  if (half == 1) {
    const float4 Ek = f4_fma(a32, Ein, S);   // inclusive state after chunk k
    f4_store_agent(&Eincl[(size_t)cidx * kU4 + u4], Ek);
    lds_e[u4] = Ein;
  }
  __threadfence();
  __syncthreads();
  if (tid == 0)
    __hip_atomic_store(&flags[cidx], 2u, __ATOMIC_RELEASE,
                       __HIP_MEMORY_SCOPE_AGENT);

  // ---- sweep 2: replay scan from registers with true seed, stream y out
  float4 seed;
  if (half == 0) {
    seed = lds_e[u4];                         // E_in
  } else {
    const float4 s0 = lds_s0[u4];
    seed = f4_fma(a16, lds_e[u4], s0);        // E_mid = a^16*E_in + s0
  }
  float4* op = reinterpret_cast<float4*>(out) + rowoff;
  float4 y = seed;
  #pragma unroll
  for (int i = 0; i < kH1; ++i) {
    y = f4_fma(a4, y, f4_mul(bb, xv[i]));
    op[(size_t)i * kU4] = y;
  }
}

// ================= 3-pass fallback =================

__global__ __launch_bounds__(256) void ema_pass1(
    const float* __restrict__ x, const float* __restrict__ bc,
    float4* __restrict__ S) {
  int g  = blockIdx.x * 256 + threadIdx.x;
  int u4 = g % kU4;
  int k  = (g / kU4) % kC3;
  int b  = g / (kU4 * kC3);
  float4 bb = reinterpret_cast<const float4*>(bc)[u4];
  float4 a4 = make_float4(1.f - bb.x, 1.f - bb.y, 1.f - bb.z, 1.f - bb.w);
  float4 s  = make_float4(0.f, 0.f, 0.f, 0.f);
  const float4* xp = reinterpret_cast<const float4*>(x)
                   + ((size_t)b * kT + (size_t)k * kL3) * kU4 + u4;
  #pragma unroll 8
  for (int i = 0; i < kL3; ++i) s = f4_fma(a4, s, f4_mul(bb, xp[(size_t)i * kU4]));
  S[((size_t)b * kC3 + k) * kU4 + u4] = s;
}

__global__ __launch_bounds__(256) void ema_pass2(
    const float4* __restrict__ S, const float* __restrict__ bc,
    float4* __restrict__ carry) {
  int g  = blockIdx.x * 256 + threadIdx.x;
  int u4 = g % kU4;
  int b  = g / kU4;
  float4 bb = reinterpret_cast<const float4*>(bc)[u4];
  float4 p = make_float4(1.f - bb.x, 1.f - bb.y, 1.f - bb.z, 1.f - bb.w);
  #pragma unroll
  for (int j = 0; j < 6; ++j) p = f4_mul(p, p);  // a^64
  float4 e = make_float4(0.f, 0.f, 0.f, 0.f);
  for (int k = 0; k < kC3; ++k) {
    size_t idx = ((size_t)b * kC3 + k) * kU4 + u4;
    carry[idx] = e;
    e = f4_fma(p, e, S[idx]);
  }
}

__global__ __launch_bounds__(256) void ema_pass3(
    const float* __restrict__ x, const float* __restrict__ bc,
    const float4* __restrict__ carry, float* __restrict__ out) {
  int g  = blockIdx.x * 256 + threadIdx.x;
  int u4 = g % kU4;
  int k  = (g / kU4) % kC3;
  int b  = g / (kU4 * kC3);
  float4 bb = reinterpret_cast<const float4*>(bc)[u4];
  float4 a4 = make_float4(1.f - bb.x, 1.f - bb.y, 1.f - bb.z, 1.f - bb.w);
  float4 y  = carry[((size_t)b * kC3 + k) * kU4 + u4];
  size_t off = ((size_t)b * kT + (size_t)k * kL3) * kU4 + u4;
  const float4* xp = reinterpret_cast<const float4*>(x) + off;
  float4*       op = reinterpret_cast<float4*>(out) + off;
  #pragma unroll 8
  for (int i = 0; i < kL3; ++i) {
    y = f4_fma(a4, y, f4_mul(bb, xp[(size_t)i * kU4]));
    op[(size_t)i * kU4] = y;
  }
}

__global__ __launch_bounds__(256) void ema_fallback(
    const float* __restrict__ x, const float* __restrict__ bc,
    float* __restrict__ out) {
  int g = blockIdx.x * 256 + threadIdx.x;
  if (g >= kB * kU4) return;
  int u4 = g % kU4;
  int b  = g / kU4;
  float4 bb = reinterpret_cast<const float4*>(bc)[u4];
  float4 a4 = make_float4(1.f - bb.x, 1.f - bb.y, 1.f - bb.z, 1.f - bb.w);
  float4 y  = make_float4(0.f, 0.f, 0.f, 0.f);
  size_t off = (size_t)b * kT * kU4 + u4;
  const float4* xp = reinterpret_cast<const float4*>(x) + off;
  float4*       op = reinterpret_cast<float4*>(out) + off;
  for (int t = 0; t < kT; ++t) {
    y = f4_fma(a4, y, f4_mul(bb, xp[(size_t)t * kU4]));
    op[(size_t)t * kU4] = y;
  }
}

}  // namespace

extern "C" void kernel_launch(void* const* d_in, const int* in_sizes, int n_in,
                              void* d_out, int out_size, void* d_ws, size_t ws_size,
                              hipStream_t stream) {
  const float* x  = (const float*)d_in[0];
  const float* bc = (const float*)d_in[1];
  float* out = (float*)d_out;

  if (ws_size >= kOnePassNeed) {
    char* wsb = (char*)d_ws;
    unsigned* ticket = (unsigned*)wsb;
    unsigned* flags  = (unsigned*)(wsb + kFlagsOff);
    float4*   Spart  = (float4*)(wsb + kSpartOff);
    float4*   Eincl  = (float4*)(wsb + kEinclOff);
    const int nzero = (int)(kSpartOff / 4);  // ticket pad + flags
    ema_zero_ws<<<(nzero + 255) / 256, 256, 0, stream>>>((unsigned*)wsb, nzero);
    ema_onepass<<<kB * kC1, 256, 0, stream>>>(x, bc, out, ticket, flags,
                                              Spart, Eincl);
    return;
  }

  const size_t S_elems = (size_t)kB * kC3 * kU4;         // float4 count
  const size_t need3 = 2ull * S_elems * sizeof(float4);  // 8 MiB
  if (ws_size >= need3) {
    float4* S     = (float4*)d_ws;
    float4* carry = S + S_elems;
    ema_pass1<<<(kB * kC3 * kU4) / 256, 256, 0, stream>>>(x, bc, S);
    ema_pass2<<<(kB * kU4) / 256, 256, 0, stream>>>(S, bc, carry);
    ema_pass3<<<(kB * kC3 * kU4) / 256, 256, 0, stream>>>(x, bc, carry, out);
  } else {
    ema_fallback<<<(kB * kU4 + 255) / 256, 256, 0, stream>>>(x, bc, out);
  }
}

// Round 3
// 203.091 us; speedup vs baseline: 9.8103x; 9.8103x over previous
//
#include <hip/hip_runtime.h>

// EMA y_t = b*x_t + (1-b)*y_{t-1}, y_{-1}=0, (B,T,U)=(32,4096,512), fp32.
//
// L3-tiled 2-kernel chunked scan, batch-grouped so the second read of x hits
// the 256 MiB Infinity Cache:
//   For each group g of 8 batches (x-slice = 64 MiB):
//     p1(g):  read slice, write chunk partials S[b][k][u4]   (slice -> L3)
//     p23(g): re-read slice (L3 hit), per-block weighted prefix over S gives
//             the chunk carry-in (pass2 fused), scan + write y.
//   Working set in p23 = 64 (x) + 64 (y) MiB < 256 MiB L3 => deterministic
//   x residency. No inter-block synchronization at all.
// Chunks: C=128 per batch, L=32 steps; block = 256 thr = 128 float4-groups x
// 2 time-halves; each thread owns 16 timesteps (kept in registers in p23).

namespace {

constexpr int kB  = 32;
constexpr int kT  = 4096;
constexpr int kU4 = 512 / 4;     // 128 float4 channel groups
constexpr int kC  = 128;         // chunks per batch
constexpr int kL  = kT / kC;     // 32 timesteps per chunk
constexpr int kH  = kL / 2;      // 16 timesteps per thread
constexpr int kBg = 8;           // batches per group
constexpr int kGroups = kB / kBg;

constexpr size_t kSElems = (size_t)kB * kC * kU4;          // float4 count
constexpr size_t kWsNeed = kSElems * sizeof(float4);       // 8 MiB

__device__ __forceinline__ float4 f4_fma(float4 a, float4 b, float4 c) {
  return make_float4(fmaf(a.x, b.x, c.x), fmaf(a.y, b.y, c.y),
                     fmaf(a.z, b.z, c.z), fmaf(a.w, b.w, c.w));
}
__device__ __forceinline__ float4 f4_mul(float4 a, float4 b) {
  return make_float4(a.x * b.x, a.y * b.y, a.z * b.z, a.w * b.w);
}
__device__ __forceinline__ float4 f4_one_minus(float4 b) {
  return make_float4(1.f - b.x, 1.f - b.y, 1.f - b.z, 1.f - b.w);
}

__global__ __launch_bounds__(256) void ema_p1(
    const float* __restrict__ x, const float* __restrict__ bc,
    float4* __restrict__ S, int b0) {
  const int k    = blockIdx.x;            // [0, kC)
  const int b    = b0 + blockIdx.y;       // absolute batch
  const int u4   = threadIdx.x & (kU4 - 1);
  const int half = threadIdx.x >> 7;

  const float4 bb = reinterpret_cast<const float4*>(bc)[u4];
  const float4 a  = f4_one_minus(bb);

  const float4* xp = reinterpret_cast<const float4*>(x)
      + ((size_t)b * kT + (size_t)k * kL + (size_t)half * kH) * kU4 + u4;
  float4 s = make_float4(0.f, 0.f, 0.f, 0.f);
  #pragma unroll
  for (int i = 0; i < kH; ++i) s = f4_fma(a, s, f4_mul(bb, xp[(size_t)i * kU4]));

  __shared__ float4 lds_s0[kU4];
  if (half == 0) lds_s0[u4] = s;
  __syncthreads();
  if (half == 1) {
    float4 a16 = a;
    #pragma unroll
    for (int j = 0; j < 4; ++j) a16 = f4_mul(a16, a16);   // a^16
    S[((size_t)b * kC + k) * kU4 + u4] = f4_fma(a16, lds_s0[u4], s);
  }
}

__global__ __launch_bounds__(256) void ema_p23(
    const float* __restrict__ x, const float* __restrict__ bc,
    const float4* __restrict__ S, float* __restrict__ out, int b0) {
  const int k    = blockIdx.x;
  const int b    = b0 + blockIdx.y;
  const int u4   = threadIdx.x & (kU4 - 1);
  const int half = threadIdx.x >> 7;

  const float4 bb = reinterpret_cast<const float4*>(bc)[u4];
  const float4 a  = f4_one_minus(bb);
  float4 a16 = a;
  #pragma unroll
  for (int j = 0; j < 4; ++j) a16 = f4_mul(a16, a16);     // a^16
  const float4 a32 = f4_mul(a16, a16);                    // a^L

  const size_t rowoff =
      ((size_t)b * kT + (size_t)k * kL + (size_t)half * kH) * kU4 + u4;
  const float4* xp = reinterpret_cast<const float4*>(x) + rowoff;

  // x sub-chunk into registers (L3-hit reads), local zero-seed partial
  float4 xv[kH];
  #pragma unroll
  for (int i = 0; i < kH; ++i) xv[i] = xp[(size_t)i * kU4];
  float4 s = make_float4(0.f, 0.f, 0.f, 0.f);
  #pragma unroll
  for (int i = 0; i < kH; ++i) s = f4_fma(a, s, f4_mul(bb, xv[i]));

  __shared__ float4 lds_s0[kU4];
  __shared__ float4 lds_e[kU4];
  if (half == 0) lds_s0[u4] = s;

  // fused pass2: carry-in E = sum_{j<k} a32^(k-1-j) * S[b][j]  (half1 only)
  if (half == 1) {
    float4 e = make_float4(0.f, 0.f, 0.f, 0.f);
    float4 w = make_float4(1.f, 1.f, 1.f, 1.f);
    const float4* Sp = S + (size_t)b * kC * kU4 + u4;
    for (int j = k - 1; j >= 0; --j) {
      e = f4_fma(w, Sp[(size_t)j * kU4], e);
      w = f4_mul(w, a32);
    }
    lds_e[u4] = e;
  }
  __syncthreads();

  const float4 Ein = lds_e[u4];
  float4 y = (half == 0) ? Ein : f4_fma(a16, Ein, lds_s0[u4]);

  float4* op = reinterpret_cast<float4*>(out) + rowoff;
  #pragma unroll
  for (int i = 0; i < kH; ++i) {
    y = f4_fma(a, y, f4_mul(bb, xv[i]));
    op[(size_t)i * kU4] = y;
  }
}

// ---- last-resort fallback: fully sequential per (b,u4) ----
__global__ __launch_bounds__(256) void ema_fallback(
    const float* __restrict__ x, const float* __restrict__ bc,
    float* __restrict__ out) {
  int g = blockIdx.x * 256 + threadIdx.x;
  if (g >= kB * kU4) return;
  int u4 = g % kU4;
  int b  = g / kU4;
  float4 bb = reinterpret_cast<const float4*>(bc)[u4];
  float4 a  = f4_one_minus(bb);
  float4 y  = make_float4(0.f, 0.f, 0.f, 0.f);
  size_t off = (size_t)b * kT * kU4 + u4;
  const float4* xp = reinterpret_cast<const float4*>(x) + off;
  float4*       op = reinterpret_cast<float4*>(out) + off;
  for (int t = 0; t < kT; ++t) {
    y = f4_fma(a, y, f4_mul(bb, xp[(size_t)t * kU4]));
    op[(size_t)t * kU4] = y;
  }
}

}  // namespace

extern "C" void kernel_launch(void* const* d_in, const int* in_sizes, int n_in,
                              void* d_out, int out_size, void* d_ws, size_t ws_size,
                              hipStream_t stream) {
  const float* x  = (const float*)d_in[0];
  const float* bc = (const float*)d_in[1];
  float* out = (float*)d_out;

  if (ws_size >= kWsNeed) {
    float4* S = (float4*)d_ws;
    for (int g = 0; g < kGroups; ++g) {
      const int b0 = g * kBg;
      ema_p1 <<<dim3(kC, kBg), 256, 0, stream>>>(x, bc, S, b0);
      ema_p23<<<dim3(kC, kBg), 256, 0, stream>>>(x, bc, S, out, b0);
    }
  } else {
    ema_fallback<<<(kB * kU4 + 255) / 256, 256, 0, stream>>>(x, bc, out);
  }
}

// Round 9
// 139.887 us; speedup vs baseline: 14.2428x; 1.4518x over previous
//
#include <hip/hip_runtime.h>

// EMA y_t = b*x_t + (1-b)*y_{t-1}, y_{-1}=0, (B,T,U)=(32,4096,512), fp32.
// rev: r8 (same algorithm as r3; resubmitted after infra failures r4-r7).
//
// Two full-width dispatches (in-order stream provides the dependency):
//   p1 : one thread per (b,chunk,u4-group); scan own 64 timesteps with zero
//        seed -> chunk partial S[b][k][u4].  Reads x (256 MiB), writes 4 MiB.
//   p23: same mapping; carry-in = backward walk over predecessors' S with
//        a^64 weights (fused pass2, <=63 L2-hit loads/thread), then scan own
//        chunk once: read x (should hit Infinity Cache: p1 just streamed
//        exactly 256 MiB = L3 size), nontemporal-store y (don't evict x).
// C=64 chunks x L=64 steps; block = 256 thr = 2 chunks x 128 u4-groups.
// Grid = 32*32 = 1024 blocks per kernel; all loads/stores 16 B coalesced.

namespace {

typedef float f4 __attribute__((ext_vector_type(4)));

constexpr int kB  = 32;
constexpr int kT  = 4096;
constexpr int kU4 = 512 / 4;     // 128 float4 channel groups
constexpr int kC  = 64;          // chunks per batch
constexpr int kL  = kT / kC;     // 64 timesteps per chunk (one thread each)

constexpr size_t kWsNeed = (size_t)kB * kC * kU4 * sizeof(f4);  // 4 MiB

__device__ __forceinline__ f4 fma4(f4 a, f4 b, f4 c) {
  f4 r;
  r.x = fmaf(a.x, b.x, c.x);
  r.y = fmaf(a.y, b.y, c.y);
  r.z = fmaf(a.z, b.z, c.z);
  r.w = fmaf(a.w, b.w, c.w);
  return r;
}

__global__ __launch_bounds__(256) void ema_p1(
    const float* __restrict__ x, const float* __restrict__ bc,
    f4* __restrict__ S) {
  const int bid  = blockIdx.x;
  const int b    = bid >> 5;            // kC/2 = 32 block-pairs per batch
  const int pair = bid & 31;
  const int sub  = threadIdx.x >> 7;    // which chunk of the pair
  const int u4   = threadIdx.x & 127;
  const int k    = pair * 2 + sub;

  const f4 bb = ((const f4*)bc)[u4];
  const f4 a  = 1.0f - bb;

  const f4* xp = (const f4*)x + ((size_t)b * kT + (size_t)k * kL) * kU4 + u4;
  f4 s = (f4)0.f;
  #pragma unroll 8
  for (int t = 0; t < kL; ++t) s = fma4(a, s, bb * xp[(size_t)t * kU4]);
  S[((size_t)b * kC + k) * kU4 + u4] = s;
}

__global__ __launch_bounds__(256) void ema_p23(
    const float* __restrict__ x, const float* __restrict__ bc,
    const f4* __restrict__ S, float* __restrict__ out) {
  const int bid  = blockIdx.x;
  const int b    = bid >> 5;
  const int pair = bid & 31;
  const int sub  = threadIdx.x >> 7;
  const int u4   = threadIdx.x & 127;
  const int k    = pair * 2 + sub;

  const f4 bb = ((const f4*)bc)[u4];
  const f4 a  = 1.0f - bb;
  f4 a64 = a;
  #pragma unroll
  for (int j = 0; j < 6; ++j) a64 *= a64;          // a^64

  // fused pass2: E_in(k) = sum_{j<k} a64^(k-1-j) * S[b][j]
  f4 e = (f4)0.f;
  f4 w = (f4)1.f;
  const f4* Sp = S + (size_t)b * kC * kU4 + u4;
  #pragma unroll 4
  for (int j = k - 1; j >= 0; --j) {
    e = fma4(w, Sp[(size_t)j * kU4], e);
    w *= a64;
  }

  // scan own chunk: x read (L3-hit hopefully), nontemporal y store
  const size_t off = ((size_t)b * kT + (size_t)k * kL) * kU4 + u4;
  const f4* xp = (const f4*)x + off;
  f4*       op = (f4*)out + off;
  f4 y = e;
  #pragma unroll 8
  for (int t = 0; t < kL; ++t) {
    y = fma4(a, y, bb * xp[(size_t)t * kU4]);
    __builtin_nontemporal_store(y, op + (size_t)t * kU4);
  }
}

// ---- last-resort fallback (ws too small): fully sequential per (b,u4) ----
__global__ __launch_bounds__(256) void ema_fallback(
    const float* __restrict__ x, const float* __restrict__ bc,
    float* __restrict__ out) {
  int g = blockIdx.x * 256 + threadIdx.x;
  if (g >= kB * kU4) return;
  int u4 = g % kU4;
  int b  = g / kU4;
  const f4 bb = ((const f4*)bc)[u4];
  const f4 a  = 1.0f - bb;
  f4 y = (f4)0.f;
  size_t off = (size_t)b * kT * kU4 + u4;
  const f4* xp = (const f4*)x + off;
  f4*       op = (f4*)out + off;
  for (int t = 0; t < kT; ++t) {
    y = fma4(a, y, bb * xp[(size_t)t * kU4]);
    op[(size_t)t * kU4] = y;
  }
}

}  // namespace

extern "C" void kernel_launch(void* const* d_in, const int* in_sizes, int n_in,
                              void* d_out, int out_size, void* d_ws, size_t ws_size,
                              hipStream_t stream) {
  const float* x  = (const float*)d_in[0];
  const float* bc = (const float*)d_in[1];
  float* out = (float*)d_out;

  if (ws_size >= kWsNeed) {
    f4* S = (f4*)d_ws;
    const int grid = kB * (kC / 2);   // 1024 blocks
    ema_p1 <<<grid, 256, 0, stream>>>(x, bc, S);
    ema_p23<<<grid, 256, 0, stream>>>(x, bc, S, out);
  } else {
    ema_fallback<<<(kB * kU4 + 255) / 256, 256, 0, stream>>>(x, bc, out);
  }
}